// Round 3
// baseline (711.777 us; speedup 1.0000x reference)
//
#include <hip/hip_runtime.h>
#include <hip/hip_bf16.h>
#include <math.h>

#define LL 65536      // H*W
#define HH 256
#define WW 256
#define BB 2
#define DIMC 128
#define QKVC 384
#define NH 8
#define CH 16

typedef __hip_bfloat16 bf16;
typedef __attribute__((ext_vector_type(8))) __bf16 bf16x8;
typedef __attribute__((ext_vector_type(4))) float f32x4;
typedef __attribute__((ext_vector_type(4))) unsigned int u32x4;

static __device__ __forceinline__ float b2f(bf16 v){ return __bfloat162float(v); }
static __device__ __forceinline__ bf16  f2b(float v){ return __float2bfloat16(v); }
static __device__ __forceinline__ unsigned short fbits(float v){
  return __builtin_bit_cast(unsigned short, __float2bfloat16(v));
}
static __device__ __forceinline__ float us2f(unsigned short u){
  return __bfloat162float(__builtin_bit_cast(bf16, u));
}

// ---------------------------------------------------------------------------
// K0: convert qkv weights [384][128] f32 -> bf16 bits.
__global__ void k_wb(const float* __restrict__ w, unsigned short* __restrict__ wb){
  int idx = blockIdx.x*256 + threadIdx.x;
  if (idx < QKVC*DIMC) wb[idx] = fbits(w[idx]);
}

// ---------------------------------------------------------------------------
// K1: pointwise qkv conv via MFMA.  Block = one 128-pixel l-tile x all 384 o.
// Epilogue: acc -> LDS (swizzled bf16) -> coalesced dwordx4 stores.
__global__ __launch_bounds__(512) void k_pw(const float* __restrict__ x,
                                            const unsigned short* __restrict__ wb,
                                            unsigned short* __restrict__ qkv){
  __shared__ u32x4 lds4[2048];              // 32 KB
  char* lds = (char*)lds4;
  unsigned short* lds16 = (unsigned short*)lds4;
  int bid = blockIdx.x;
  int b = bid >> 9;
  int l0 = (bid & 511) << 7;
  int tid = threadIdx.x;
  const float* xb = x + (size_t)b*DIMC*LL;

  // stage x tile f32->bf16 into LDS [l=128][c=128], 16B granules XOR-swizzled
  #pragma unroll
  for (int it=0; it<4; ++it){
    int task = it*512 + tid;
    int l   = task & 127;
    int oct = task >> 7;
    float v[8];
    #pragma unroll
    for (int e=0;e<8;++e) v[e] = xb[(size_t)(oct*8+e)*LL + l0 + l];
    u32x4 p;
    #pragma unroll
    for (int k=0;k<4;++k){
      unsigned lo = fbits(v[2*k]);
      unsigned hi = fbits(v[2*k+1]);
      p[k] = lo | (hi<<16);
    }
    *(u32x4*)(lds + l*256 + ((oct ^ (l&15))<<4)) = p;
  }
  __syncthreads();

  int wid = tid >> 6, lane = tid & 63;
  int r = lane & 15, kg = lane >> 4;
  int ob = wid * 48;
  f32x4 acc[3][8];
  #pragma unroll
  for (int ft=0; ft<3; ++ft)
    #pragma unroll
    for (int nt=0; nt<8; ++nt) acc[ft][nt] = (f32x4)0.f;

  #pragma unroll
  for (int kb=0; kb<4; ++kb){
    bf16x8 a[3], bf[8];
    #pragma unroll
    for (int ft=0; ft<3; ++ft)
      a[ft] = *(const bf16x8*)(wb + (size_t)(ob + ft*16 + r)*DIMC + kb*32 + kg*8);
    #pragma unroll
    for (int nt=0; nt<8; ++nt){
      int l = nt*16 + r;
      bf[nt] = *(const bf16x8*)(lds + l*256 + (((kb*4 + kg) ^ r)<<4));
    }
    #pragma unroll
    for (int ft=0; ft<3; ++ft)
      #pragma unroll
      for (int nt=0; nt<8; ++nt)
        acc[ft][nt] = __builtin_amdgcn_mfma_f32_16x16x32_bf16(a[ft], bf[nt], acc[ft][nt], 0,0,0);
  }

  // epilogue: per ft-third, transpose through LDS, store coalesced
  unsigned short* qb = qkv + (size_t)b*QKVC*LL + l0;
  int gl = tid & 15;
  int rowid = tid >> 4;                     // 0..31
  #pragma unroll
  for (int ft=0; ft<3; ++ft){
    __syncthreads();
    #pragma unroll
    for (int nt=0; nt<8; ++nt)
      #pragma unroll
      for (int i=0;i<4;++i){
        int o_l = wid*16 + kg*4 + i;        // 0..127 local o within this ft
        int l = nt*16 + r;
        lds16[o_l*128 + (((l>>3) ^ ((o_l>>1)&7))<<3) + (l&7)] = fbits(acc[ft][nt][i]);
      }
    __syncthreads();
    #pragma unroll
    for (int j=0;j<4;++j){
      int o_l = rowid*4 + j;
      u32x4 v = *(u32x4*)(lds16 + o_l*128 + ((gl ^ ((o_l>>1)&7))<<3));
      int o_g = (o_l>>4)*48 + ft*16 + (o_l&15);
      *(u32x4*)(qb + (size_t)o_g*LL + gl*8) = v;
    }
  }
}

// ---------------------------------------------------------------------------
// K2: fused depthwise-3x3 + Gram for q,k.  Block = (b, head, 16-row band).
// Per 4-row sub-chunk: dw in registers (shfl for x+-1), dw output -> swizzled
// LDS fragment tiles, then 3 MFMAs (qk, qq, kk) accumulate; atomicAdd reduce.
__global__ __launch_bounds__(512) void k_dwg(const unsigned short* __restrict__ qkvp,
                                             const float* __restrict__ dww,
                                             float* __restrict__ S,
                                             float* __restrict__ nq,
                                             float* __restrict__ nk){
  __shared__ unsigned short q_l[16*1024];   // 32 KB  [ch=16][px=1024] swizzled
  __shared__ unsigned short k_l[16*1024];   // 32 KB
  int bid = blockIdx.x;
  int band = bid & 15;
  int h    = (bid >> 4) & 7;
  int b    = bid >> 7;
  int tid  = threadIdx.x;
  int col  = tid & 255;
  int tch  = tid >> 8;        // 0/1: two channels processed in parallel
  int lane = tid & 63;
  int wid  = tid >> 6;
  int r = lane & 15, kg = lane >> 4;

  f32x4 sqk = (f32x4)0.f, sqq = (f32x4)0.f, skk = (f32x4)0.f;

  for (int sub=0; sub<4; ++sub){
    int r0 = band*16 + sub*4;               // 4 output rows per sub
    for (int it=0; it<16; ++it){
      int cc  = it*2 + tch;                 // 0..31
      int isk = cc >> 4;
      int c   = cc & 15;
      int och = isk*DIMC + h*CH + c;
      const unsigned short* src = qkvp + ((size_t)b*QKVC + och)*LL;
      const float* w9 = dww + och*9;
      float w0=w9[0],w1=w9[1],w2=w9[2],w3=w9[3],w4=w9[4],w5=w9[5],w6=w9[6],w7=w9[7],w8=w9[8];
      unsigned short* dst = (isk ? k_l : q_l) + c*1024;
      float a0l,a0c,a0r,a1l,a1c,a1r;
      {
        int rr = r0-1;
        float xc = (rr>=0) ? us2f(src[rr*WW + col]) : 0.f;
        float xl = __shfl_up(xc,1);
        float xr = __shfl_down(xc,1);
        if (lane==0)  xl = (rr>=0 && col>0)    ? us2f(src[rr*WW + col-1]) : 0.f;
        if (lane==63) xr = (rr>=0 && col<WW-1) ? us2f(src[rr*WW + col+1]) : 0.f;
        a0l=xl; a0c=xc; a0r=xr;
      }
      {
        int rr = r0;
        float xc = us2f(src[rr*WW + col]);
        float xl = __shfl_up(xc,1);
        float xr = __shfl_down(xc,1);
        if (lane==0)  xl = (col>0)    ? us2f(src[rr*WW + col-1]) : 0.f;
        if (lane==63) xr = (col<WW-1) ? us2f(src[rr*WW + col+1]) : 0.f;
        a1l=xl; a1c=xc; a1r=xr;
      }
      #pragma unroll
      for (int rw=0; rw<4; ++rw){
        int rr = r0 + rw + 1;
        bool rok = (rr < HH);
        float xc = rok ? us2f(src[rr*WW + col]) : 0.f;
        float xl = __shfl_up(xc,1);
        float xr = __shfl_down(xc,1);
        if (lane==0)  xl = (rok && col>0)    ? us2f(src[rr*WW + col-1]) : 0.f;
        if (lane==63) xr = (rok && col<WW-1) ? us2f(src[rr*WW + col+1]) : 0.f;
        float acc;
        acc = w0*a0l;               acc = fmaf(w1,a0c,acc); acc = fmaf(w2,a0r,acc);
        acc = fmaf(w3,a1l,acc);     acc = fmaf(w4,a1c,acc); acc = fmaf(w5,a1r,acc);
        acc = fmaf(w6,xl, acc);     acc = fmaf(w7,xc, acc); acc = fmaf(w8,xr, acc);
        int px = rw*256 + col;
        dst[(((px>>3) ^ c)<<3) + (px&7)] = fbits(acc);
        a0l=a1l; a0c=a1c; a0r=a1r;
        a1l=xl;  a1c=xc;  a1r=xr;
      }
    }
    __syncthreads();
    #pragma unroll
    for (int kl=0; kl<4; ++kl){
      int p = (wid*4 + kl)*4 + kg;          // octet 0..127
      bf16x8 qf = *(const bf16x8*)(q_l + r*1024 + ((p ^ r)<<3));
      bf16x8 kf = *(const bf16x8*)(k_l + r*1024 + ((p ^ r)<<3));
      sqk = __builtin_amdgcn_mfma_f32_16x16x32_bf16(qf, kf, sqk, 0,0,0);
      sqq = __builtin_amdgcn_mfma_f32_16x16x32_bf16(qf, qf, sqq, 0,0,0);
      skk = __builtin_amdgcn_mfma_f32_16x16x32_bf16(kf, kf, skk, 0,0,0);
    }
    __syncthreads();
  }
  float* Sb = S + (size_t)((b*NH + h)*CH)*CH;
  #pragma unroll
  for (int i=0;i<4;++i)
    atomicAdd(&Sb[(kg*4+i)*CH + r], sqk[i]);
  if ((r>>2) == kg){
    int i = r&3;
    atomicAdd(&nq[(b*NH+h)*CH + r], sqq[i]);
    atomicAdd(&nk[(b*NH+h)*CH + r], skk[i]);
  }
}

// ---------------------------------------------------------------------------
// K4: finalize attention; fold proj -> per-batch M2[o][j] bf16.
__global__ __launch_bounds__(256) void k_fin(const float* __restrict__ S,
                                             const float* __restrict__ nq,
                                             const float* __restrict__ nk,
                                             const float* __restrict__ temp,
                                             const float* __restrict__ attca,
                                             const float* __restrict__ proj,
                                             unsigned short* __restrict__ M2){
  int b = blockIdx.x;
  int t = threadIdx.x;
  __shared__ float attnf[NH][CH][CH];
  __shared__ float pl[DIMC*DIMC];
  for (int idx=t; idx<DIMC*DIMC; idx+=256) pl[idx] = proj[idx];
  if (t < 128){
    int h = t >> 4, c = t & 15;
    float tmpv = temp[h];
    float qn = fmaxf(sqrtf(nq[(b*NH+h)*CH + c]), 1e-12f);
    float row[CH], ex[CH], a1[CH];
    float m = -1e30f;
    #pragma unroll
    for (int d=0; d<CH; ++d){
      float kn = fmaxf(sqrtf(nk[(b*NH+h)*CH + d]), 1e-12f);
      float v = S[((b*NH+h)*CH + c)*CH + d] / (qn*kn) * tmpv;
      row[d] = v;
      m = fmaxf(m, v);
    }
    float sum = 0.f;
    #pragma unroll
    for (int d=0;d<CH;++d){ ex[d] = expf(row[d]-m); sum += ex[d]; }
    float inv = 1.f/sum;
    #pragma unroll
    for (int d=0;d<CH;++d){
      float rr = fmaxf(row[d], 0.f);
      float xx = rr*rr;
      float g = 0.5f * xx * (1.f + erff(xx * 0.70710678118654752440f));
      a1[d] = g * xx;
    }
    #pragma unroll
    for (int j=0;j<CH;++j){
      float sc=0.f, sh=0.f;
      #pragma unroll
      for (int i=0;i<CH;++i){
        sc = fmaf(attca[j*CH+i],      a1[i], sc);
        sh = fmaf(attca[(CH+j)*CH+i], a1[i], sh);
      }
      attnf[h][c][j] = ex[j]*inv*(1.f+sc) + sh;
    }
  }
  __syncthreads();
  for (int idx=t; idx<DIMC*DIMC; idx+=256){
    int o = idx >> 7, j = idx & 127;
    int h = j >> 4, d = j & 15;
    float s = 0.f;
    #pragma unroll
    for (int c2=0;c2<CH;++c2) s = fmaf(pl[o*DIMC + h*CH + c2], attnf[h][c2][d], s);
    M2[(size_t)b*DIMC*DIMC + o*DIMC + j] = fbits(s);
  }
}

// ---------------------------------------------------------------------------
// K5: fused dw-v + out GEMM.  Block = one 128-px l-tile (half image row).
// Staging computes the 3x3 depthwise conv on v inline (shfl for x+-1) and
// writes the swizzled B-tile; then MFMA with M2 A-frags; f32 stores.
__global__ __launch_bounds__(256) void k_out(const unsigned short* __restrict__ qkvp,
                                             const float* __restrict__ dww,
                                             const unsigned short* __restrict__ M2,
                                             float* __restrict__ out){
  __shared__ u32x4 lds4[2048];              // 32 KB: [l=128][j=128] bf16 swizzled
  char* lds = (char*)lds4;
  int bid = blockIdx.x;
  int b = bid >> 9;
  int lt = bid & 511;
  int row  = lt >> 1;
  int col0 = (lt & 1) << 7;
  int l0 = row*WW + col0;
  int tid = threadIdx.x;
  int lane = tid & 63;
  int p = tid & 127;                        // px within tile
  int gcol = col0 + p;
  const unsigned short* vb = qkvp + ((size_t)b*QKVC + 2*DIMC)*LL;

  #pragma unroll
  for (int ii=0; ii<8; ++ii){
    int oct = (tid>>7)*8 + ii;              // 0..15
    u32x4 pk;
    #pragma unroll
    for (int e2=0; e2<4; ++e2){
      unsigned lohi[2];
      #pragma unroll
      for (int hf=0; hf<2; ++hf){
        int ch = oct*8 + e2*2 + hf;
        const unsigned short* s = vb + (size_t)ch*LL;
        const float* w9 = dww + (size_t)(2*DIMC + ch)*9;
        float acc = 0.f;
        #pragma unroll
        for (int dy=-1; dy<=1; ++dy){
          int rr = row + dy;
          bool rok = (rr>=0 && rr<HH);
          float xc = rok ? us2f(s[rr*WW + gcol]) : 0.f;
          float xl = __shfl_up(xc,1);
          float xr = __shfl_down(xc,1);
          if (lane==0)  xl = (rok && gcol>0)    ? us2f(s[rr*WW + gcol-1]) : 0.f;
          if (lane==63) xr = (rok && gcol<WW-1) ? us2f(s[rr*WW + gcol+1]) : 0.f;
          acc = fmaf(xl, w9[(dy+1)*3+0], acc);
          acc = fmaf(xc, w9[(dy+1)*3+1], acc);
          acc = fmaf(xr, w9[(dy+1)*3+2], acc);
        }
        lohi[hf] = fbits(acc);
      }
      pk[e2] = lohi[0] | (lohi[1]<<16);
    }
    *(u32x4*)(lds + p*256 + ((oct ^ (p&15))<<4)) = pk;
  }
  __syncthreads();

  int wid = tid >> 6;
  int r = lane & 15, kg = lane >> 4;
  int ob = wid * 32;
  f32x4 acc[2][8];
  #pragma unroll
  for (int ft=0; ft<2; ++ft)
    #pragma unroll
    for (int nt=0; nt<8; ++nt) acc[ft][nt] = (f32x4)0.f;

  #pragma unroll
  for (int kb=0; kb<4; ++kb){
    bf16x8 a[2], bf[8];
    #pragma unroll
    for (int ft=0; ft<2; ++ft)
      a[ft] = *(const bf16x8*)(M2 + (size_t)b*DIMC*DIMC + (ob + ft*16 + r)*DIMC + kb*32 + kg*8);
    #pragma unroll
    for (int nt=0; nt<8; ++nt){
      int l = nt*16 + r;
      bf[nt] = *(const bf16x8*)(lds + l*256 + (((kb*4 + kg) ^ r)<<4));
    }
    #pragma unroll
    for (int ft=0; ft<2; ++ft)
      #pragma unroll
      for (int nt=0; nt<8; ++nt)
        acc[ft][nt] = __builtin_amdgcn_mfma_f32_16x16x32_bf16(a[ft], bf[nt], acc[ft][nt], 0,0,0);
  }

  float* ob_ptr = out + (size_t)b*DIMC*LL + l0;
  #pragma unroll
  for (int ft=0; ft<2; ++ft)
    #pragma unroll
    for (int nt=0; nt<8; ++nt)
      #pragma unroll
      for (int i=0;i<4;++i){
        int o = ob + ft*16 + kg*4 + i;
        ob_ptr[(size_t)o*LL + nt*16 + r] = acc[ft][nt][i];
      }
}

// ---------------------------------------------------------------------------
extern "C" void kernel_launch(void* const* d_in, const int* in_sizes, int n_in,
                              void* d_out, int out_size, void* d_ws, size_t ws_size,
                              hipStream_t stream){
  const float* x      = (const float*)d_in[0];
  const float* qkv_w  = (const float*)d_in[1];
  const float* dw_w   = (const float*)d_in[2];
  const float* proj_w = (const float*)d_in[3];
  const float* attca  = (const float*)d_in[4];
  const float* temp   = (const float*)d_in[5];
  float* out = (float*)d_out;

  char* ws = (char*)d_ws;
  size_t off = 0;
  unsigned short* qkv_pw = (unsigned short*)(ws + off); off += (size_t)BB*QKVC*LL*2;
  float* S  = (float*)(ws + off); off += (size_t)BB*NH*CH*CH*4;
  float* nq = (float*)(ws + off); off += (size_t)BB*NH*CH*4;
  float* nk = (float*)(ws + off); off += (size_t)BB*NH*CH*4;
  unsigned short* wb = (unsigned short*)(ws + off); off += (size_t)QKVC*DIMC*2;
  unsigned short* M2 = (unsigned short*)(ws + off); off += (size_t)BB*DIMC*DIMC*2;

  hipMemsetAsync(S, 0, (size_t)(BB*NH*CH*CH + 2*BB*NH*CH)*4, stream);

  k_wb  <<<(QKVC*DIMC + 255)/256, 256, 0, stream>>>(qkv_w, wb);
  k_pw  <<<BB*512,       512, 0, stream>>>(x, wb, qkv_pw);
  k_dwg <<<BB*NH*16,     512, 0, stream>>>(qkv_pw, dw_w, S, nq, nk);
  k_fin <<<BB,           256, 0, stream>>>(S, nq, nk, temp, attca, proj_w, M2);
  k_out <<<BB*512,       256, 0, stream>>>(qkv_pw, dw_w, M2, out);
}

// Round 6
// 254.698 us; speedup vs baseline: 2.7946x; 2.7946x over previous
//
#include <hip/hip_runtime.h>
#include <hip/hip_bf16.h>
#include <math.h>

#define LL 65536      // H*W
#define HH 256
#define WW 256
#define BB 2
#define DIMC 128
#define QKVC 384
#define NH 8
#define CH 16

typedef __hip_bfloat16 bf16;
typedef __attribute__((ext_vector_type(8))) __bf16 bf16x8;
typedef __attribute__((ext_vector_type(4))) float f32x4;
typedef __attribute__((ext_vector_type(4))) unsigned int u32x4;

static __device__ __forceinline__ float b2f(bf16 v){ return __bfloat162float(v); }
static __device__ __forceinline__ unsigned short fbits(float v){
  return __builtin_bit_cast(unsigned short, __float2bfloat16(v));
}
static __device__ __forceinline__ float us2f(unsigned short u){
  return __bfloat162float(__builtin_bit_cast(bf16, u));
}

// ---------------------------------------------------------------------------
// K0: convert qkv weights [384][128] f32 -> bf16 bits.
__global__ void k_wb(const float* __restrict__ w, unsigned short* __restrict__ wb){
  int idx = blockIdx.x*256 + threadIdx.x;
  if (idx < QKVC*DIMC) wb[idx] = fbits(w[idx]);
}

// ---------------------------------------------------------------------------
// K1: pointwise qkv conv via MFMA.  Block = one 128-pixel l-tile x all 384 o.
// Epilogue: acc -> LDS (swizzled bf16) -> coalesced dwordx4 stores.
__global__ __launch_bounds__(512) void k_pw(const float* __restrict__ x,
                                            const unsigned short* __restrict__ wb,
                                            unsigned short* __restrict__ qkv){
  __shared__ u32x4 lds4[2048];              // 32 KB
  char* lds = (char*)lds4;
  unsigned short* lds16 = (unsigned short*)lds4;
  int bid = blockIdx.x;
  int b = bid >> 9;
  int l0 = (bid & 511) << 7;
  int tid = threadIdx.x;
  const float* xb = x + (size_t)b*DIMC*LL;

  #pragma unroll
  for (int it=0; it<4; ++it){
    int task = it*512 + tid;
    int l   = task & 127;
    int oct = task >> 7;
    float v[8];
    #pragma unroll
    for (int e=0;e<8;++e) v[e] = xb[(size_t)(oct*8+e)*LL + l0 + l];
    u32x4 p;
    #pragma unroll
    for (int k=0;k<4;++k){
      unsigned lo = fbits(v[2*k]);
      unsigned hi = fbits(v[2*k+1]);
      p[k] = lo | (hi<<16);
    }
    *(u32x4*)(lds + l*256 + ((oct ^ (l&15))<<4)) = p;
  }
  __syncthreads();

  int wid = tid >> 6, lane = tid & 63;
  int r = lane & 15, kg = lane >> 4;
  int ob = wid * 48;
  f32x4 acc[3][8];
  #pragma unroll
  for (int ft=0; ft<3; ++ft)
    #pragma unroll
    for (int nt=0; nt<8; ++nt) acc[ft][nt] = (f32x4)0.f;

  #pragma unroll
  for (int kb=0; kb<4; ++kb){
    bf16x8 a[3], bf[8];
    #pragma unroll
    for (int ft=0; ft<3; ++ft)
      a[ft] = *(const bf16x8*)(wb + (size_t)(ob + ft*16 + r)*DIMC + kb*32 + kg*8);
    #pragma unroll
    for (int nt=0; nt<8; ++nt){
      int l = nt*16 + r;
      bf[nt] = *(const bf16x8*)(lds + l*256 + (((kb*4 + kg) ^ r)<<4));
    }
    #pragma unroll
    for (int ft=0; ft<3; ++ft)
      #pragma unroll
      for (int nt=0; nt<8; ++nt)
        acc[ft][nt] = __builtin_amdgcn_mfma_f32_16x16x32_bf16(a[ft], bf[nt], acc[ft][nt], 0,0,0);
  }

  unsigned short* qb = qkv + (size_t)b*QKVC*LL + l0;
  int gl = tid & 15;
  int rowid = tid >> 4;
  #pragma unroll
  for (int ft=0; ft<3; ++ft){
    __syncthreads();
    #pragma unroll
    for (int nt=0; nt<8; ++nt)
      #pragma unroll
      for (int i=0;i<4;++i){
        int o_l = wid*16 + kg*4 + i;
        int l = nt*16 + r;
        lds16[o_l*128 + (((l>>3) ^ ((o_l>>1)&7))<<3) + (l&7)] = fbits(acc[ft][nt][i]);
      }
    __syncthreads();
    #pragma unroll
    for (int j=0;j<4;++j){
      int o_l = rowid*4 + j;
      u32x4 v = *(u32x4*)(lds16 + o_l*128 + ((gl ^ ((o_l>>1)&7))<<3));
      int o_g = (o_l>>4)*48 + ft*16 + (o_l&15);
      *(u32x4*)(qb + (size_t)o_g*LL + gl*8) = v;
    }
  }
}

// ---------------------------------------------------------------------------
// K2: 3x3 depthwise conv, register-only vectorized.  Block = (b, ch, 8-row
// band).  Thread = one 8-px strip of one output row: 3 x ushort8 loads
// (rows -1..+1), x+-1 halo via shfl (image-edge masked), 72 FMA, 1 store.
__global__ __launch_bounds__(256) void k_dw(const unsigned short* __restrict__ src_,
                                            const float* __restrict__ dw,
                                            unsigned short* __restrict__ dst_){
  int bid = blockIdx.x;
  int band = bid & 31;
  int ch = (bid >> 5) % QKVC;
  int b  = bid / (QKVC*32);
  int t = threadIdx.x;
  int rowl = t >> 5;            // 0..7
  int seg  = t & 31;            // 8-px strip within the 256-px row
  int grow = band*8 + rowl;
  const unsigned short* src = src_ + ((size_t)b*QKVC + ch)*LL;
  const float* w9 = dw + ch*9;

  float v[3][8];
  #pragma unroll
  for (int dy=0; dy<3; ++dy){
    int rr = grow + dy - 1;
    if (rr >= 0 && rr < HH){
      u32x4 raw = *(const u32x4*)(src + (size_t)rr*WW + seg*8);
      #pragma unroll
      for (int k=0;k<4;++k){
        v[dy][2*k]   = us2f((unsigned short)(raw[k] & 0xffffu));
        v[dy][2*k+1] = us2f((unsigned short)(raw[k] >> 16));
      }
    } else {
      #pragma unroll
      for (int e=0;e<8;++e) v[dy][e] = 0.f;
    }
  }
  int lane = t & 63;
  float lft[3], rgt[3];
  #pragma unroll
  for (int dy=0; dy<3; ++dy){
    float lv = __shfl(v[dy][7], lane-1);
    float rv = __shfl(v[dy][0], lane+1);
    lft[dy] = (seg==0)  ? 0.f : lv;
    rgt[dy] = (seg==31) ? 0.f : rv;
  }
  float w0=w9[0],w1=w9[1],w2=w9[2],w3=w9[3],w4=w9[4],w5=w9[5],w6=w9[6],w7=w9[7],w8=w9[8];
  float o[8];
  #pragma unroll
  for (int e=0;e<8;++e){
    float l0 = (e==0) ? lft[0] : v[0][e-1];
    float l1 = (e==0) ? lft[1] : v[1][e-1];
    float l2 = (e==0) ? lft[2] : v[2][e-1];
    float r0 = (e==7) ? rgt[0] : v[0][e+1];
    float r1 = (e==7) ? rgt[1] : v[1][e+1];
    float r2 = (e==7) ? rgt[2] : v[2][e+1];
    float a;
    a = w0*l0;            a = fmaf(w1, v[0][e], a); a = fmaf(w2, r0, a);
    a = fmaf(w3, l1, a);  a = fmaf(w4, v[1][e], a); a = fmaf(w5, r1, a);
    a = fmaf(w6, l2, a);  a = fmaf(w7, v[2][e], a); a = fmaf(w8, r2, a);
    o[e] = a;
  }
  u32x4 pk;
  #pragma unroll
  for (int k=0;k<4;++k){
    unsigned lo = fbits(o[2*k]);
    unsigned hi = fbits(o[2*k+1]);
    pk[k] = lo | (hi<<16);
  }
  *(u32x4*)(dst_ + ((size_t)b*QKVC + ch)*LL + (size_t)grow*WW + seg*8) = pk;
}

// ---------------------------------------------------------------------------
// K3: Gram matrices via MFMA from global fragments.  3 MFMAs per k-step:
// S=q.k^T, qq^T (diag -> ||q||^2), kk^T (diag -> ||k||^2).  atomicAdd reduce.
__global__ __launch_bounds__(256) void k_gram(const unsigned short* __restrict__ qkvd,
                                              float* __restrict__ S,
                                              float* __restrict__ nq,
                                              float* __restrict__ nk){
  int bid = blockIdx.x;
  int chunk = bid & 63;
  int h = (bid>>6)&7;
  int b = bid>>9;
  int tid = threadIdx.x, wid = tid>>6, lane = tid&63;
  int r = lane&15, kg = lane>>4;
  int l0 = chunk*1024 + wid*256;
  const unsigned short* qb = qkvd + (size_t)(b*QKVC + h*CH)*LL;
  const unsigned short* kb = qkvd + (size_t)(b*QKVC + DIMC + h*CH)*LL;
  f32x4 sqk = (f32x4)0.f, sqq = (f32x4)0.f, skk = (f32x4)0.f;
  #pragma unroll 4
  for (int ks=0; ks<8; ++ks){
    int l = l0 + ks*32 + kg*8;
    bf16x8 qf = *(const bf16x8*)(qb + (size_t)r*LL + l);
    bf16x8 kf = *(const bf16x8*)(kb + (size_t)r*LL + l);
    sqk = __builtin_amdgcn_mfma_f32_16x16x32_bf16(qf, kf, sqk, 0,0,0);
    sqq = __builtin_amdgcn_mfma_f32_16x16x32_bf16(qf, qf, sqq, 0,0,0);
    skk = __builtin_amdgcn_mfma_f32_16x16x32_bf16(kf, kf, skk, 0,0,0);
  }
  float* Sb = S + (size_t)((b*NH + h)*CH)*CH;
  #pragma unroll
  for (int i=0;i<4;++i)
    atomicAdd(&Sb[(kg*4+i)*CH + r], sqk[i]);
  if ((r>>2) == kg){
    int i = r&3;
    atomicAdd(&nq[(b*NH+h)*CH + r], sqq[i]);
    atomicAdd(&nk[(b*NH+h)*CH + r], skk[i]);
  }
}

// ---------------------------------------------------------------------------
// K4: finalize attention; fold proj -> per-batch M2[o][j] bf16.
__global__ __launch_bounds__(256) void k_fin(const float* __restrict__ S,
                                             const float* __restrict__ nq,
                                             const float* __restrict__ nk,
                                             const float* __restrict__ temp,
                                             const float* __restrict__ attca,
                                             const float* __restrict__ proj,
                                             unsigned short* __restrict__ M2){
  int b = blockIdx.x;
  int t = threadIdx.x;
  __shared__ float attnf[NH][CH][CH];
  __shared__ float pl[DIMC*DIMC];
  for (int idx=t; idx<DIMC*DIMC; idx+=256) pl[idx] = proj[idx];
  if (t < 128){
    int h = t >> 4, c = t & 15;
    float tmpv = temp[h];
    float qn = fmaxf(sqrtf(nq[(b*NH+h)*CH + c]), 1e-12f);
    float row[CH], ex[CH], a1[CH];
    float m = -1e30f;
    #pragma unroll
    for (int d=0; d<CH; ++d){
      float kn = fmaxf(sqrtf(nk[(b*NH+h)*CH + d]), 1e-12f);
      float v = S[((b*NH+h)*CH + c)*CH + d] / (qn*kn) * tmpv;
      row[d] = v;
      m = fmaxf(m, v);
    }
    float sum = 0.f;
    #pragma unroll
    for (int d=0;d<CH;++d){ ex[d] = expf(row[d]-m); sum += ex[d]; }
    float inv = 1.f/sum;
    #pragma unroll
    for (int d=0;d<CH;++d){
      float rr = fmaxf(row[d], 0.f);
      float xx = rr*rr;
      float g = 0.5f * xx * (1.f + erff(xx * 0.70710678118654752440f));
      a1[d] = g * xx;
    }
    #pragma unroll
    for (int j=0;j<CH;++j){
      float sc=0.f, sh=0.f;
      #pragma unroll
      for (int i=0;i<CH;++i){
        sc = fmaf(attca[j*CH+i],      a1[i], sc);
        sh = fmaf(attca[(CH+j)*CH+i], a1[i], sh);
      }
      attnf[h][c][j] = ex[j]*inv*(1.f+sc) + sh;
    }
  }
  __syncthreads();
  for (int idx=t; idx<DIMC*DIMC; idx+=256){
    int o = idx >> 7, j = idx & 127;
    int h = j >> 4, d = j & 15;
    float s = 0.f;
    #pragma unroll
    for (int c2=0;c2<CH;++c2) s = fmaf(pl[o*DIMC + h*CH + c2], attnf[h][c2][d], s);
    M2[(size_t)b*DIMC*DIMC + o*DIMC + j] = fbits(s);
  }
}

// ---------------------------------------------------------------------------
// K5: out[o][l] = sum_j M2[o][j] V[j][l] via MFMA.  V tile transposed inline
// into swizzled LDS [l][j]; A-frags from global M2 (L1-resident); f32 stores.
__global__ __launch_bounds__(256) void k_out(const unsigned short* __restrict__ qkvd,
                                             const unsigned short* __restrict__ M2,
                                             float* __restrict__ out){
  __shared__ u32x4 lds4[2048];              // 32 KB: [l=128][j=128] bf16 swizzled
  char* lds = (char*)lds4;
  int bid = blockIdx.x;
  int b = bid >> 9;
  int l0 = (bid & 511) << 7;
  int tid = threadIdx.x;
  const unsigned short* vb = qkvd + (size_t)(b*QKVC + 2*DIMC)*LL;

  #pragma unroll
  for (int it=0; it<4; ++it){
    int task = it*256 + tid;
    int lp  = (task & 63) * 2;
    int oct = task >> 6;
    unsigned lo32[8];
    #pragma unroll
    for (int e=0;e<8;++e)
      lo32[e] = *(const unsigned int*)(vb + (size_t)(oct*8+e)*LL + l0 + lp);
    u32x4 p0, p1;
    #pragma unroll
    for (int k=0;k<4;++k){
      unsigned a0 = lo32[2*k] & 0xffffu,  a1 = lo32[2*k] >> 16;
      unsigned b0 = lo32[2*k+1] & 0xffffu, b1 = lo32[2*k+1] >> 16;
      p0[k] = a0 | (b0<<16);
      p1[k] = a1 | (b1<<16);
    }
    *(u32x4*)(lds + lp*256     + ((oct ^ (lp&15))<<4))     = p0;
    *(u32x4*)(lds + (lp+1)*256 + ((oct ^ ((lp+1)&15))<<4)) = p1;
  }
  __syncthreads();

  int wid = tid >> 6, lane = tid & 63;
  int r = lane & 15, kg = lane >> 4;
  int ob = wid * 32;
  f32x4 acc[2][8];
  #pragma unroll
  for (int ft=0; ft<2; ++ft)
    #pragma unroll
    for (int nt=0; nt<8; ++nt) acc[ft][nt] = (f32x4)0.f;

  #pragma unroll
  for (int kb=0; kb<4; ++kb){
    bf16x8 a[2], bf[8];
    #pragma unroll
    for (int ft=0; ft<2; ++ft)
      a[ft] = *(const bf16x8*)(M2 + (size_t)b*DIMC*DIMC + (ob + ft*16 + r)*DIMC + kb*32 + kg*8);
    #pragma unroll
    for (int nt=0; nt<8; ++nt){
      int l = nt*16 + r;
      bf[nt] = *(const bf16x8*)(lds + l*256 + (((kb*4 + kg) ^ r)<<4));
    }
    #pragma unroll
    for (int ft=0; ft<2; ++ft)
      #pragma unroll
      for (int nt=0; nt<8; ++nt)
        acc[ft][nt] = __builtin_amdgcn_mfma_f32_16x16x32_bf16(a[ft], bf[nt], acc[ft][nt], 0,0,0);
  }

  float* ob_ptr = out + (size_t)b*DIMC*LL + l0;
  #pragma unroll
  for (int ft=0; ft<2; ++ft)
    #pragma unroll
    for (int nt=0; nt<8; ++nt)
      #pragma unroll
      for (int i=0;i<4;++i){
        int o = ob + ft*16 + kg*4 + i;
        ob_ptr[(size_t)o*LL + nt*16 + r] = acc[ft][nt][i];
      }
}

// ---------------------------------------------------------------------------
extern "C" void kernel_launch(void* const* d_in, const int* in_sizes, int n_in,
                              void* d_out, int out_size, void* d_ws, size_t ws_size,
                              hipStream_t stream){
  const float* x      = (const float*)d_in[0];
  const float* qkv_w  = (const float*)d_in[1];
  const float* dw_w   = (const float*)d_in[2];
  const float* proj_w = (const float*)d_in[3];
  const float* attca  = (const float*)d_in[4];
  const float* temp   = (const float*)d_in[5];
  float* out = (float*)d_out;

  char* ws = (char*)d_ws;
  size_t off = 0;
  unsigned short* qkv_pw = (unsigned short*)(ws + off); off += (size_t)BB*QKVC*LL*2;
  unsigned short* qkv_dw = (unsigned short*)(ws + off); off += (size_t)BB*QKVC*LL*2;
  float* S  = (float*)(ws + off); off += (size_t)BB*NH*CH*CH*4;
  float* nq = (float*)(ws + off); off += (size_t)BB*NH*CH*4;
  float* nk = (float*)(ws + off); off += (size_t)BB*NH*CH*4;
  unsigned short* wb = (unsigned short*)(ws + off); off += (size_t)QKVC*DIMC*2;
  unsigned short* M2 = (unsigned short*)(ws + off); off += (size_t)BB*DIMC*DIMC*2;

  hipMemsetAsync(S, 0, (size_t)(BB*NH*CH*CH + 2*BB*NH*CH)*4, stream);

  k_wb  <<<(QKVC*DIMC + 255)/256, 256, 0, stream>>>(qkv_w, wb);
  k_pw  <<<BB*512,       512, 0, stream>>>(x, wb, qkv_pw);
  k_dw  <<<BB*QKVC*32,   256, 0, stream>>>(qkv_pw, dw_w, qkv_dw);
  k_gram<<<BB*512,       256, 0, stream>>>(qkv_dw, S, nq, nk);
  k_fin <<<BB,           256, 0, stream>>>(S, nq, nk, temp, attca, proj_w, M2);
  k_out <<<BB*512,       256, 0, stream>>>(qkv_dw, M2, out);
}